// Round 1
// baseline (8439.090 us; speedup 1.0000x reference)
//
#include <hip/hip_runtime.h>
#include <math.h>

#define NN    325
#define BB    64
#define HD    64
#define MM    5
#define TT    12
#define NP    384          // padded n (6*64)
#define KP    336          // padded k (21*16)
#define JMAX  8192         // row stride for mats buffers
#define NODE  4096         // 64*64 per-node stride of h buffers
#define BNHF  (NN*NODE)    // floats per h buffer
#define MS    (NP*JMAX)    // floats per mat buffer

// ---------------------------------------------------------------- setup ----
__global__ void k_sums(const float* __restrict__ adj, float* __restrict__ rs,
                       float* __restrict__ cs){
  int j = blockIdx.x*256 + threadIdx.x;
  if (j >= NN) return;
  float a = 0.f, b = 0.f;
  for (int k = 0; k < NN; ++k){ a += adj[j*NN + k]; b += adj[k*NN + j]; }
  rs[j] = a; cs[j] = b;
}

// ST[s][k*NP + n] = S_s[n][k]  (zero padded).  S1[i][j]=adj[j][i]/rowsum[j],
// S2[i][j]=adj[i][j]/colsum[j]
__global__ void k_build_S(const float* __restrict__ adj, const float* __restrict__ rs,
                          const float* __restrict__ cs, float* __restrict__ ST){
  int idx = blockIdx.x*256 + threadIdx.x;   // grid covers KP*NP exactly
  int k = idx / NP, n = idx - k*NP;
  float s1 = 0.f, s2 = 0.f;
  if (k < NN && n < NN){
    s1 = adj[k*NN + n] / rs[k];
    s2 = adj[n*NN + k] / cs[k];
  }
  ST[idx] = s1;
  ST[KP*NP + idx] = s2;
}

// inpT[t][n][b] = inputs[t][b][n]
__global__ void k_inpT(const float* __restrict__ inp, float* __restrict__ inpT){
  __shared__ float tile[64][65];
  int t = blockIdx.y, n0 = blockIdx.x*64;
  int lane = threadIdx.x & 63, g = threadIdx.x >> 6;
  #pragma unroll
  for (int r = 0; r < 16; ++r){
    int b = r*4 + g;
    tile[b][lane] = (n0 + lane < NN) ? inp[(t*BB + b)*NN + n0 + lane] : 0.f;
  }
  __syncthreads();
  #pragma unroll
  for (int r = 0; r < 16; ++r){
    int c2 = r*4 + g;
    if (n0 + c2 < NN) inpT[t*(NN*64) + (n0 + c2)*64 + lane] = tile[lane][c2];
  }
}

// h_l[n*NODE + c*64 + b] = init_state[l][b][n*64+c]
__global__ void k_initT(const float* __restrict__ init, float* __restrict__ h0,
                        float* __restrict__ h1){
  __shared__ float tile[64][65];
  int n = blockIdx.x, l = blockIdx.y;
  int lane = threadIdx.x & 63, g = threadIdx.x >> 6;
  const float* src = init + (size_t)l*BB*NN*HD;
  #pragma unroll
  for (int r = 0; r < 16; ++r){
    int b = r*4 + g;
    tile[b][lane] = src[(size_t)b*NN*HD + n*HD + lane];
  }
  __syncthreads();
  float* dst = (l == 0) ? h0 : h1;
  #pragma unroll
  for (int r = 0; r < 16; ++r){
    int c2 = r*4 + g;
    dst[n*NODE + c2*64 + lane] = tile[lane][c2];
  }
}

// zero pad rows [NN, KP) of mats[0] (contiguous block)
__global__ void k_zeropad(float* __restrict__ m0){
  int idx = blockIdx.x*256 + threadIdx.x;   // grid covers (KP-NN)*JMAX exactly
  m0[NN*JMAX + idx] = 0.f;
}

// ------------------------------------------------------------- per-step ----
// mats0[n][j], j in [jstart, J): j < CA64 -> srcA[n*strideA + j]
//                                else     -> srcB[n*NODE + j - CA64]
__global__ void k_concat(const float* __restrict__ srcA, int strideA, int CA64,
                         const float* __restrict__ srcB, float* __restrict__ m0,
                         int jstart, int J){
  int n = blockIdx.y;
  int j = jstart + blockIdx.x*256 + threadIdx.x;
  if (j >= J) return;
  float v = (j < CA64) ? srcA[n*strideA + j] : srcB[n*NODE + (j - CA64)];
  m0[n*JMAX + j] = v;
}

// Out_s = S_s @ X_s (optionally cheb: Out = 2*S@X - Cin).  Tiles: 64n x 128j,
// thread = 8n x 4j.  grid = (jtiles, 6, 2)
template<bool CHEB>
__global__ __launch_bounds__(256)
void k_spmm(const float* __restrict__ STb, const float* __restrict__ Xb, int Xstride,
            float* __restrict__ Ob, int Ostride, const float* __restrict__ Cin,
            int jbase, int J){
  int s = blockIdx.z;
  const float* ST = STb + s*(KP*NP);
  const float* X  = Xb + (size_t)s*Xstride;
  float* Out      = Ob + (size_t)s*Ostride;
  int n0 = blockIdx.y*64;
  int j0 = jbase + blockIdx.x*128;
  __shared__ float ldsS[16][64];
  __shared__ float ldsX[16][128];
  int tid = threadIdx.x;
  int bj = (tid & 31)*4;
  int bn = (tid >> 5)*8;
  float acc[8][4];
  #pragma unroll
  for (int i = 0; i < 8; ++i)
    #pragma unroll
    for (int q = 0; q < 4; ++q) acc[i][q] = 0.f;

  for (int k0 = 0; k0 < KP; k0 += 16){
    {
      int flat = tid*4;
      int k = flat >> 6, nn = flat & 63;
      *(float4*)&ldsS[k][nn] = *(const float4*)&ST[(k0 + k)*NP + n0 + nn];
    }
    #pragma unroll
    for (int r = 0; r < 2; ++r){
      int flat = (tid + r*256)*4;
      int k = flat >> 7, jl = flat & 127;
      float4 v = make_float4(0.f, 0.f, 0.f, 0.f);
      if (j0 + jl < J) v = *(const float4*)&X[(k0 + k)*JMAX + j0 + jl];
      *(float4*)&ldsX[k][jl] = v;
    }
    __syncthreads();
    #pragma unroll
    for (int k = 0; k < 16; ++k){
      float sv[8], xv[4];
      *(float4*)&sv[0] = *(float4*)&ldsS[k][bn];
      *(float4*)&sv[4] = *(float4*)&ldsS[k][bn + 4];
      *(float4*)&xv[0] = *(float4*)&ldsX[k][bj];
      #pragma unroll
      for (int i = 0; i < 8; ++i)
        #pragma unroll
        for (int q = 0; q < 4; ++q)
          acc[i][q] += sv[i]*xv[q];
    }
    __syncthreads();
  }
  #pragma unroll
  for (int i = 0; i < 8; ++i){
    int n = n0 + bn + i;
    if (n >= KP) continue;               // rows >= 336 never consumed
    int rowo = n*JMAX + j0 + bj;
    #pragma unroll
    for (int q = 0; q < 4; ++q){
      if (j0 + bj + q < J){
        float v = acc[i][q];
        if (CHEB) v = 2.f*v - Cin[rowo + q];
        Out[rowo + q] = v;
      }
    }
  }
}

// out[b*N+n][o] = sum_{c,m} mats[m][n][c*64+b] * W[(c*5+m)*O + o] + bias[o]
// MODE 0 (gate, O=128, grid.y=2): oy0 -> rh = sigmoid(.)*h ; oy1 -> uu = sigmoid(.)
// MODE 1 (cand, O=64, grid.y=1): h = uu*h + (1-uu)*tanh(.)
template<int MODE>
__global__ __launch_bounds__(256)
void k_wgemm(const float* __restrict__ mats, const float* __restrict__ W,
             const float* __restrict__ bias, int C,
             float* __restrict__ h, float* __restrict__ rh, float* __restrict__ uu){
  const int O = (MODE == 0) ? 128 : 64;
  int n = blockIdx.x;
  int oy = blockIdx.y;
  int o0 = oy*64;
  __shared__ float ldsA[20][64];
  __shared__ float ldsW[20][64];
  int tid = threadIdx.x;
  int b4 = (tid & 15)*4, o4 = (tid >> 4)*4;
  float acc[4][4] = {};
  int nchunk = (C + 3) >> 2;
  for (int cc = 0; cc < nchunk; ++cc){
    int c0 = cc*4;
    #pragma unroll
    for (int r = 0; r < 5; ++r){
      int flat = tid + r*256;
      int row = flat >> 6, col = flat & 63;
      int c = c0 + row/5, m = row % 5;
      float av = 0.f, wv = 0.f;
      if (c < C){
        av = mats[(size_t)m*MS + n*JMAX + c*64 + col];
        wv = W[(c*MM + m)*O + o0 + col];
      }
      ldsA[row][col] = av;
      ldsW[row][col] = wv;
    }
    __syncthreads();
    #pragma unroll
    for (int kk = 0; kk < 20; ++kk){
      float av[4], wv[4];
      *(float4*)av = *(float4*)&ldsA[kk][b4];
      *(float4*)wv = *(float4*)&ldsW[kk][o4];
      #pragma unroll
      for (int bi = 0; bi < 4; ++bi)
        #pragma unroll
        for (int oi = 0; oi < 4; ++oi)
          acc[bi][oi] += av[bi]*wv[oi];
    }
    __syncthreads();
  }
  #pragma unroll
  for (int oi = 0; oi < 4; ++oi){
    int o = o4 + oi;
    float bv = bias[o0 + o];
    #pragma unroll
    for (int bi = 0; bi < 4; ++bi){
      int b = b4 + bi;
      float v = acc[bi][oi] + bv;
      int idx = n*NODE + o*64 + b;
      if (MODE == 0){
        float sg = 1.f/(1.f + expf(-v));
        if (oy == 0) rh[idx] = sg*h[idx];
        else         uu[idx] = sg;
      } else {
        float cv = tanhf(v);
        float u = uu[idx];
        h[idx] = u*h[idx] + (1.f - u)*cv;
      }
    }
  }
}

// out[b*N + n] = sum_j h1[n][j][b]*Wfc[j] + bfc
__global__ void k_fc(const float* __restrict__ h1, const float* __restrict__ Wfc,
                     const float* __restrict__ bfc, float* __restrict__ out){
  int n = blockIdx.x*4 + (threadIdx.x >> 6);
  int b = threadIdx.x & 63;
  if (n >= NN) return;
  float acc = bfc[0];
  #pragma unroll
  for (int j = 0; j < 64; ++j) acc += h1[n*NODE + j*64 + b]*Wfc[j];
  out[b*NN + n] = acc;
}

// ----------------------------------------------------------------- host ----
extern "C" void kernel_launch(void* const* d_in, const int* in_sizes, int n_in,
                              void* d_out, int out_size, void* d_ws, size_t ws_size,
                              hipStream_t stream){
  const float* inp  = (const float*)d_in[0];
  const float* init = (const float*)d_in[1];
  const float* adj  = (const float*)d_in[2];
  const float* Wg0  = (const float*)d_in[3];
  const float* bg0  = (const float*)d_in[4];
  const float* Wc0  = (const float*)d_in[5];
  const float* bc0  = (const float*)d_in[6];
  const float* Wg1  = (const float*)d_in[7];
  const float* bg1  = (const float*)d_in[8];
  const float* Wc1  = (const float*)d_in[9];
  const float* bc1  = (const float*)d_in[10];
  const float* Wfc  = (const float*)d_in[11];
  const float* bfc  = (const float*)d_in[12];
  (void)in_sizes; (void)n_in; (void)out_size; (void)ws_size;

  float* ws   = (float*)d_ws;
  float* ST   = ws;
  float* rs   = ST + 2L*KP*NP;
  float* cs   = rs + 512;
  float* inpT = cs + 512;
  float* h0   = inpT + (long)TT*NN*64;
  float* h1   = h0 + BNHF;
  float* rh   = h1 + BNHF;
  float* uu   = rh + BNHF;
  float* mats = uu + BNHF;          // 5 * MS floats
  float* out  = (float*)d_out;

  hipMemsetAsync(out, 0, (size_t)BB*NN*sizeof(float), stream);  // output row 0
  k_sums<<<2, 256, 0, stream>>>(adj, rs, cs);
  k_build_S<<<(KP*NP)/256, 256, 0, stream>>>(adj, rs, cs, ST);
  k_inpT<<<dim3(6, TT), 256, 0, stream>>>(inp, inpT);
  k_initT<<<dim3(NN, 2), 256, 0, stream>>>(init, h0, h1);
  k_zeropad<<<((KP - NN)*JMAX)/256, 256, 0, stream>>>(mats);

  for (int t = 0; t < TT; ++t){
    const float* xin = inpT + (long)t*NN*64;
    // ---------------- layer 0 (C=65, J=4160) ----------------
    // gate
    k_concat<<<dim3(17, NN), 256, 0, stream>>>(xin, 64, 64, h0, mats, 0, 4160);
    k_spmm<false><<<dim3(33, 6, 2), 256, 0, stream>>>(ST, mats, 0, mats + MS, 2*MS, nullptr, 0, 4160);
    k_spmm<true ><<<dim3(33, 6, 2), 256, 0, stream>>>(ST, mats + MS, 2*MS, mats + 2*MS, 2*MS, mats, 0, 4160);
    k_wgemm<0><<<dim3(NN, 2), 256, 0, stream>>>(mats, Wg0, bg0, 65, h0, rh, uu);
    // candidate
    k_concat<<<dim3(17, NN), 256, 0, stream>>>(xin, 64, 64, rh, mats, 0, 4160);
    k_spmm<false><<<dim3(33, 6, 2), 256, 0, stream>>>(ST, mats, 0, mats + MS, 2*MS, nullptr, 0, 4160);
    k_spmm<true ><<<dim3(33, 6, 2), 256, 0, stream>>>(ST, mats + MS, 2*MS, mats + 2*MS, 2*MS, mats, 0, 4160);
    k_wgemm<1><<<dim3(NN, 1), 256, 0, stream>>>(mats, Wc0, bc0, 65, h0, rh, uu);
    // ---------------- layer 1 (C=128, J=8192) ----------------
    // gate (full)
    k_concat<<<dim3(32, NN), 256, 0, stream>>>(h0, NODE, NODE, h1, mats, 0, 8192);
    k_spmm<false><<<dim3(64, 6, 2), 256, 0, stream>>>(ST, mats, 0, mats + MS, 2*MS, nullptr, 0, 8192);
    k_spmm<true ><<<dim3(64, 6, 2), 256, 0, stream>>>(ST, mats + MS, 2*MS, mats + 2*MS, 2*MS, mats, 0, 8192);
    k_wgemm<0><<<dim3(NN, 2), 256, 0, stream>>>(mats, Wg1, bg1, 128, h1, rh, uu);
    // candidate: x-part (cols < 4096) identical to gate -> recompute only rh half
    k_concat<<<dim3(16, NN), 256, 0, stream>>>(h0, NODE, NODE, rh, mats, 4096, 8192);
    k_spmm<false><<<dim3(32, 6, 2), 256, 0, stream>>>(ST, mats, 0, mats + MS, 2*MS, nullptr, 4096, 8192);
    k_spmm<true ><<<dim3(32, 6, 2), 256, 0, stream>>>(ST, mats + MS, 2*MS, mats + 2*MS, 2*MS, mats, 4096, 8192);
    k_wgemm<1><<<dim3(NN, 1), 256, 0, stream>>>(mats, Wc1, bc1, 128, h1, rh, uu);
    // output
    k_fc<<<82, 256, 0, stream>>>(h1, Wfc, bfc, out + (size_t)(t + 1)*BB*NN);
  }
}

// Round 2
// 2914.762 us; speedup vs baseline: 2.8953x; 2.8953x over previous
//
#include <hip/hip_runtime.h>
#include <math.h>

#define NN    325
#define BB    64
#define HD    64
#define TT    12
#define NODE  4096          // per-node stride of fp32 h buffers: [n][c<64][b<64]
#define KD    352           // padded node dim (K of S-applications), 11*32
#define NPADR 384           // padded S rows (24 M-tiles of 16)
#define XP    360           // LDS pitch (nodes) for diff kernel

typedef __attribute__((ext_vector_type(8))) short short8v;
typedef __attribute__((ext_vector_type(4))) short short4v;
typedef __attribute__((ext_vector_type(4))) float float4v;

__device__ __forceinline__ unsigned short f2bf(float f){
  unsigned u = __builtin_bit_cast(unsigned, f);
  u += 0x7fffu + ((u >> 16) & 1u);          // RNE
  return (unsigned short)(u >> 16);
}
__device__ __forceinline__ float bf2f(unsigned short h){
  unsigned u = ((unsigned)h) << 16;
  return __builtin_bit_cast(float, u);
}

// ---------------------------------------------------------------- setup ----
__global__ void k_sums(const float* __restrict__ adj, float* __restrict__ rs,
                       float* __restrict__ cs){
  int j = blockIdx.x*256 + threadIdx.x;
  if (j >= NN) return;
  float a = 0.f, b = 0.f;
  for (int k = 0; k < NN; ++k){ a += adj[j*NN + k]; b += adj[k*NN + j]; }
  rs[j] = a; cs[j] = b;
}

// Sb[s][i][j] (i<NPADR rows=dest, j<KD cols=src), bf16, zero padded.
// S1[i][j]=adj[j][i]/rs[j], S2[i][j]=adj[i][j]/cs[j]
__global__ void k_build_Sb(const float* __restrict__ adj, const float* __restrict__ rs,
                           const float* __restrict__ cs, unsigned short* __restrict__ Sb){
  int idx = blockIdx.x*256 + threadIdx.x;      // grid covers 2*NPADR*KD exactly
  int s = idx / (NPADR*KD);
  int rem = idx - s*(NPADR*KD);
  int i = rem / KD, j = rem - i*KD;
  float v = 0.f;
  if (i < NN && j < NN)
    v = (s == 0) ? adj[j*NN + i]/rs[j] : adj[i*NN + j]/cs[j];
  Sb[idx] = f2bf(v);
}

// Wt[o][k], k = m*C + c, from W[(c*5+m)*O + o]; zero for k >= 5C
__global__ void k_buildWt(const float* __restrict__ W, unsigned short* __restrict__ Wt,
                          int C, int O, int Kpad){
  int idx = blockIdx.x*256 + threadIdx.x;      // grid covers O*Kpad exactly
  int o = idx / Kpad, k = idx - o*Kpad;
  int m = k / C, c = k - m*C;
  float v = (m < 5) ? W[(c*5 + m)*O + o] : 0.f;
  Wt[idx] = f2bf(v);
}

// inpT[t][n][b] = inputs[t][b][n]
__global__ void k_inpT(const float* __restrict__ inp, float* __restrict__ inpT){
  __shared__ float tile[64][65];
  int t = blockIdx.y, n0 = blockIdx.x*64;
  int lane = threadIdx.x & 63, g = threadIdx.x >> 6;
  #pragma unroll
  for (int r = 0; r < 16; ++r){
    int b = r*4 + g;
    tile[b][lane] = (n0 + lane < NN) ? inp[(t*BB + b)*NN + n0 + lane] : 0.f;
  }
  __syncthreads();
  #pragma unroll
  for (int r = 0; r < 16; ++r){
    int c2 = r*4 + g;
    if (n0 + c2 < NN) inpT[t*(NN*64) + (n0 + c2)*64 + lane] = tile[lane][c2];
  }
}

// h_l[n*NODE + c*64 + b] = init_state[l][b][n*64+c]
__global__ void k_initT(const float* __restrict__ init, float* __restrict__ h0,
                        float* __restrict__ h1){
  __shared__ float tile[64][65];
  int n = blockIdx.x, l = blockIdx.y;
  int lane = threadIdx.x & 63, g = threadIdx.x >> 6;
  const float* src = init + (size_t)l*BB*NN*HD;
  #pragma unroll
  for (int r = 0; r < 16; ++r){
    int b = r*4 + g;
    tile[b][lane] = src[(size_t)b*NN*HD + n*HD + lane];
  }
  __syncthreads();
  float* dst = (l == 0) ? h0 : h1;
  #pragma unroll
  for (int r = 0; r < 16; ++r){
    int c2 = r*4 + g;
    dst[n*NODE + c2*64 + lane] = tile[lane][c2];
  }
}

// ------------------------------------------------- fused diffusion kernel ----
// One MFMA pass: Out = S @ XB  (optionally cheb: Out = 2*S@XB - X0).
// Writes Out rows (<NN) to mats[n][mk][b] bf16 and (TOLDS) to XO[b][node].
template<bool CHEB, bool TOLDS>
__device__ __forceinline__ void diff_pass(
    const unsigned short* __restrict__ S,
    unsigned short (*XB)[XP], unsigned short (*XO)[XP], unsigned short (*X0)[XP],
    unsigned short* __restrict__ mats, int mk, int Kpad, int w, int r, int g)
{
  float4v acc[6][4];
  #pragma unroll
  for (int i = 0; i < 6; ++i)
    #pragma unroll
    for (int j = 0; j < 4; ++j) acc[i][j] = (float4v){0.f,0.f,0.f,0.f};

  for (int kc = 0; kc < KD/32; ++kc){
    short8v a[6], bb[4];
    #pragma unroll
    for (int mt = 0; mt < 6; ++mt){
      int row = (w*6 + mt)*16 + r;
      a[mt] = *(const short8v*)&S[(size_t)row*KD + kc*32 + g*8];
    }
    #pragma unroll
    for (int nt = 0; nt < 4; ++nt)
      bb[nt] = *(const short8v*)&XB[nt*16 + r][kc*32 + g*8];
    #pragma unroll
    for (int mt = 0; mt < 6; ++mt)
      #pragma unroll
      for (int nt = 0; nt < 4; ++nt)
        acc[mt][nt] = __builtin_amdgcn_mfma_f32_16x16x32_bf16(a[mt], bb[nt], acc[mt][nt], 0, 0, 0);
  }
  #pragma unroll
  for (int mt = 0; mt < 6; ++mt){
    int node0 = (w*6 + mt)*16 + g*4;
    if (node0 >= KD) continue;           // rows >= 352 never used
    #pragma unroll
    for (int nt = 0; nt < 4; ++nt){
      int col = nt*16 + r;
      float4v v = acc[mt][nt];
      short4v pk;
      if (CHEB){
        short4v x0v = *(short4v*)&X0[col][node0];
        #pragma unroll
        for (int i = 0; i < 4; ++i)
          pk[i] = (short)f2bf(2.f*v[i] - bf2f((unsigned short)x0v[i]));
      } else {
        #pragma unroll
        for (int i = 0; i < 4; ++i) pk[i] = (short)f2bf(v[i]);
      }
      if (TOLDS) *(short4v*)&XO[col][node0] = pk;
      #pragma unroll
      for (int i = 0; i < 4; ++i){
        int n = node0 + i;
        if (n < NN) mats[((size_t)n*Kpad + mk)*64 + col] = (unsigned short)pk[i];
      }
    }
  }
}

// grid = (numChannels, 2 supports), block = 256.  Channel c = cbase+bx.
// x0(n,c,b) = c<csplit ? srcA[n*strideA + c*64+b] : srcB[n*NODE + (c-csplit)*64+b]
__global__ __launch_bounds__(256) void k_diff(
    const unsigned short* __restrict__ Sb, const float* __restrict__ srcA, int strideA,
    int csplit, const float* __restrict__ srcB, unsigned short* __restrict__ mats,
    int C, int Kpad, int cbase)
{
  __shared__ unsigned short X0[64][XP];
  __shared__ unsigned short X1[64][XP];
  int c = cbase + blockIdx.x;
  int s = blockIdx.y;
  int t = threadIdx.x;
  int b = t & 63, w = t >> 6;
  int r = t & 15, g = (t >> 4) & 3;

  // stage x0 (transposed, bf16) + mats0 (s==0 only)
  for (int o8 = w; o8 < KD/8; o8 += 4){
    int n0 = o8*8;
    short8v pk;
    #pragma unroll
    for (int i = 0; i < 8; ++i){
      int n = n0 + i;
      float v = 0.f;
      if (n < NN)
        v = (c < csplit) ? srcA[(size_t)n*strideA + c*64 + b]
                         : srcB[(size_t)n*NODE + (c - csplit)*64 + b];
      pk[i] = (short)f2bf(v);
    }
    *(short8v*)&X0[b][n0] = pk;
    if (s == 0){
      #pragma unroll
      for (int i = 0; i < 8; ++i){
        int n = n0 + i;
        if (n < NN) mats[((size_t)n*Kpad + c)*64 + b] = (unsigned short)pk[i];
      }
    }
  }
  __syncthreads();
  const unsigned short* S = Sb + (size_t)s * NPADR * KD;
  diff_pass<false, true >(S, X0, X1, X0, mats, (1 + 2*s)*C + c, Kpad, w, r, g);
  __syncthreads();
  diff_pass<true , false>(S, X1, X1, X0, mats, (2 + 2*s)*C + c, Kpad, w, r, g);
}

// ------------------------------------------------------- W-GEMM (MFMA) ----
// Per node n: D[o][b] = sum_k Wt[o][k] * mats[n][k][b].
// MODE 0: O=128: o<64 -> rh = sigm*h ; o>=64 -> uu = sigm
// MODE 1: O=64 : h = uu*h + (1-uu)*tanh ; FC: fuse out = h_new @ Wfc + bfc
template<int KPAD, int MODE, bool FC>
__global__ __launch_bounds__(256) void k_wg(
    const unsigned short* __restrict__ mats, const unsigned short* __restrict__ Wt,
    const float* __restrict__ bias, float* __restrict__ h,
    float* __restrict__ rh, float* __restrict__ uu,
    const float* __restrict__ Wfc, const float* __restrict__ bfc,
    float* __restrict__ outp)
{
  __shared__ unsigned short XT[64][KPAD + 8];
  __shared__ float fcbuf[64];
  int n = blockIdx.x;
  int t = threadIdx.x, b = t & 63, w = t >> 6;
  int r = t & 15, g = (t >> 4) & 3;
  if (FC && t < 64) fcbuf[t] = 0.f;

  for (int o8 = w; o8 < KPAD/8; o8 += 4){
    int k0 = o8*8;
    short8v pk;
    #pragma unroll
    for (int i = 0; i < 8; ++i)
      pk[i] = (short)mats[((size_t)n*KPAD + k0 + i)*64 + b];
    *(short8v*)&XT[b][k0] = pk;
  }
  __syncthreads();

  const int OT = (MODE == 0) ? 2 : 1;
  float4v acc[OT][4];
  #pragma unroll
  for (int j = 0; j < OT; ++j)
    #pragma unroll
    for (int nt = 0; nt < 4; ++nt) acc[j][nt] = (float4v){0.f,0.f,0.f,0.f};

  for (int kc = 0; kc < KPAD/32; ++kc){
    short8v a[OT], bb[4];
    #pragma unroll
    for (int j = 0; j < OT; ++j){
      int o = (w + 4*j)*16 + r;
      a[j] = *(const short8v*)&Wt[(size_t)o*KPAD + kc*32 + g*8];
    }
    #pragma unroll
    for (int nt = 0; nt < 4; ++nt)
      bb[nt] = *(const short8v*)&XT[nt*16 + r][kc*32 + g*8];
    #pragma unroll
    for (int j = 0; j < OT; ++j)
      #pragma unroll
      for (int nt = 0; nt < 4; ++nt)
        acc[j][nt] = __builtin_amdgcn_mfma_f32_16x16x32_bf16(a[j], bb[nt], acc[j][nt], 0, 0, 0);
  }

  #pragma unroll
  for (int j = 0; j < OT; ++j){
    #pragma unroll
    for (int nt = 0; nt < 4; ++nt){
      int b2 = nt*16 + r;
      float p = 0.f;
      #pragma unroll
      for (int i = 0; i < 4; ++i){
        int o = (w + 4*j)*16 + g*4 + i;
        float v = acc[j][nt][i] + bias[o];
        if (MODE == 0){
          float sg = 1.f/(1.f + expf(-v));
          if (o < 64){
            size_t idx = (size_t)n*NODE + o*64 + b2;
            rh[idx] = sg * h[idx];
          } else {
            uu[(size_t)n*NODE + (o - 64)*64 + b2] = sg;
          }
        } else {
          float cv = tanhf(v);
          size_t idx = (size_t)n*NODE + o*64 + b2;
          float uv = uu[idx];
          float hn = uv*h[idx] + (1.f - uv)*cv;
          h[idx] = hn;
          if (FC) p += hn * Wfc[o];
        }
      }
      if (FC) atomicAdd(&fcbuf[b2], p);
    }
  }
  if (FC){
    __syncthreads();
    if (t < 64) outp[(size_t)t*NN + n] = fcbuf[t] + bfc[0];
  }
}

// ----------------------------------------------------------------- host ----
extern "C" void kernel_launch(void* const* d_in, const int* in_sizes, int n_in,
                              void* d_out, int out_size, void* d_ws, size_t ws_size,
                              hipStream_t stream){
  const float* inp  = (const float*)d_in[0];
  const float* init = (const float*)d_in[1];
  const float* adj  = (const float*)d_in[2];
  const float* Wg0  = (const float*)d_in[3];
  const float* bg0  = (const float*)d_in[4];
  const float* Wc0  = (const float*)d_in[5];
  const float* bc0  = (const float*)d_in[6];
  const float* Wg1  = (const float*)d_in[7];
  const float* bg1  = (const float*)d_in[8];
  const float* Wc1  = (const float*)d_in[9];
  const float* bc1  = (const float*)d_in[10];
  const float* Wfc  = (const float*)d_in[11];
  const float* bfc  = (const float*)d_in[12];
  (void)in_sizes; (void)n_in; (void)out_size; (void)ws_size;

  char* p = (char*)d_ws;
  auto alloc = [&](size_t bytes) -> void* {
    void* q = (void*)p; p += (bytes + 255) & ~(size_t)255; return q;
  };
  unsigned short* Sb    = (unsigned short*)alloc((size_t)2*NPADR*KD*2);
  unsigned short* Wg0t  = (unsigned short*)alloc((size_t)128*352*2);
  unsigned short* Wc0t  = (unsigned short*)alloc((size_t)64*352*2);
  unsigned short* Wg1t  = (unsigned short*)alloc((size_t)128*640*2);
  unsigned short* Wc1t  = (unsigned short*)alloc((size_t)64*640*2);
  float* rs    = (float*)alloc(512*4);
  float* cs    = (float*)alloc(512*4);
  float* inpT  = (float*)alloc((size_t)TT*NN*64*4);
  float* h0    = (float*)alloc((size_t)NN*NODE*4);
  float* h1    = (float*)alloc((size_t)NN*NODE*4);
  float* rh    = (float*)alloc((size_t)NN*NODE*4);
  float* uu    = (float*)alloc((size_t)NN*NODE*4);
  unsigned short* matsL0 = (unsigned short*)alloc((size_t)NN*352*64*2);
  unsigned short* matsL1 = (unsigned short*)alloc((size_t)NN*640*64*2);
  float* out = (float*)d_out;

  hipMemsetAsync(out, 0, (size_t)BB*NN*sizeof(float), stream);   // output row 0
  k_sums<<<2, 256, 0, stream>>>(adj, rs, cs);
  k_build_Sb<<<(2*NPADR*KD)/256, 256, 0, stream>>>(adj, rs, cs, Sb);
  k_buildWt<<<(128*352)/256, 256, 0, stream>>>(Wg0, Wg0t, 65, 128, 352);
  k_buildWt<<<( 64*352)/256, 256, 0, stream>>>(Wc0, Wc0t, 65,  64, 352);
  k_buildWt<<<(128*640)/256, 256, 0, stream>>>(Wg1, Wg1t, 128, 128, 640);
  k_buildWt<<<( 64*640)/256, 256, 0, stream>>>(Wc1, Wc1t, 128,  64, 640);
  k_inpT<<<dim3(6, TT), 256, 0, stream>>>(inp, inpT);
  k_initT<<<dim3(NN, 2), 256, 0, stream>>>(init, h0, h1);

  for (int t = 0; t < TT; ++t){
    const float* xin = inpT + (size_t)t*NN*64;
    // ---- layer 0 gate ----
    k_diff<<<dim3(65, 2), 256, 0, stream>>>(Sb, xin, 64, 1, h0, matsL0, 65, 352, 0);
    k_wg<352, 0, false><<<NN, 256, 0, stream>>>(matsL0, Wg0t, bg0, h0, rh, uu,
                                                nullptr, nullptr, nullptr);
    // ---- layer 0 candidate (c=0 x-part reused from gate) ----
    k_diff<<<dim3(64, 2), 256, 0, stream>>>(Sb, xin, 64, 1, rh, matsL0, 65, 352, 1);
    k_wg<352, 1, false><<<NN, 256, 0, stream>>>(matsL0, Wc0t, bc0, h0, rh, uu,
                                                nullptr, nullptr, nullptr);
    // ---- layer 1 gate ----
    k_diff<<<dim3(128, 2), 256, 0, stream>>>(Sb, h0, NODE, 64, h1, matsL1, 128, 640, 0);
    k_wg<640, 0, false><<<NN, 256, 0, stream>>>(matsL1, Wg1t, bg1, h1, rh, uu,
                                                nullptr, nullptr, nullptr);
    // ---- layer 1 candidate (c<64 x-part reused from gate) + fused fc ----
    k_diff<<<dim3(64, 2), 256, 0, stream>>>(Sb, h0, NODE, 64, rh, matsL1, 128, 640, 64);
    k_wg<640, 1, true><<<NN, 256, 0, stream>>>(matsL1, Wc1t, bc1, h1, rh, uu,
                                               Wfc, bfc, out + (size_t)(t + 1)*BB*NN);
  }
}